// Round 14
// baseline (587.459 us; speedup 1.0000x reference)
//
#include <hip/hip_runtime.h>
#include <hip/hip_bf16.h>

#define N_NODES 100000
#define N_EDGES 3200000
#define F_IN    512
#define HID     256
#define C_OUT   40

#define RPB     512                 // rows per bucket
#define BSHIFT  9
#define NBUCK   196                 // ceil(100000/512)
#define CAP     20480               // slots per bucket (mean 16384 + 32 sigma)
#define GSTR    16                  // gfill padding (ints) -> 64B per counter
#define SLICE_B 32                  // fp8 bytes per feature slice (256/8)

typedef unsigned short u16;
typedef unsigned char  u8;
typedef unsigned int   u32;
typedef __attribute__((ext_vector_type(8))) short bf16x8;
typedef __attribute__((ext_vector_type(4))) float f32x4;
typedef __attribute__((ext_vector_type(2))) float f32x2;

__device__ __forceinline__ u16 f2bf(float f) {
    u32 x = __float_as_uint(f);
    return (u16)((x + 0x7fffu + ((x >> 16) & 1u)) >> 16);  // RNE
}
__device__ __forceinline__ u32 pk2(float lo, float hi) {
    return (u32)f2bf(lo) | ((u32)f2bf(hi) << 16);
}

// ---------------- prep: W1 transpose->bf16, W2 pad->bf16, zero gfill ----------------

__global__ __launch_bounds__(256) void k_prep(const float* __restrict__ W1,
                                              const float* __restrict__ W2,
                                              u16* __restrict__ W1t,
                                              u16* __restrict__ W2t,
                                              int* __restrict__ gfill) {
    int b = blockIdx.x, t = threadIdx.x;
    if (b < 512) {                       // W1t[n][k] = bf16(W1[k][n])
        int i = b * 256 + t;             // over 512*256
        int k = i >> 8, n = i & 255;
        W1t[(size_t)n * F_IN + k] = f2bf(W1[i]);
    } else if (b < 576) {                // W2t[n][k], classes 40..63 zero
        int i = (b - 512) * 256 + t;     // over 64*256
        int n = i >> 8, k = i & 255;
        W2t[i] = (n < C_OUT) ? f2bf(W2[k * C_OUT + n]) : (u16)0;
    } else {
        for (int j = t; j < NBUCK * GSTR; j += 256) gfill[j] = 0;
    }
}

// ---------------- CSR build: two-pass bucket counting sort ----------------

__global__ __launch_bounds__(1024) void k_p1(const int* __restrict__ row,
                                             const int* __restrict__ col,
                                             const float* __restrict__ val,
                                             int* __restrict__ gfill,     // [NBUCK*GSTR]
                                             int2* __restrict__ bpack) {  // [NBUCK*CAP]
    __shared__ int hist[NBUCK];
    __shared__ int base[NBUCK];
    int t = threadIdx.x;
    for (int j = t; j < NBUCK; j += 1024) hist[j] = 0;
    __syncthreads();
    int e0 = blockIdx.x * 4096;
    int bin[4], key[4], lr[4];
    float vl[4];
#pragma unroll
    for (int u = 0; u < 4; u++) {
        int i = e0 + u * 1024 + t;
        if (i < N_EDGES) {
            int r = row[i];
            bin[u] = r >> BSHIFT;
            key[u] = (col[i] << BSHIFT) | (r & (RPB - 1));
            vl[u] = val[i];
            lr[u] = atomicAdd(&hist[bin[u]], 1);
        } else {
            bin[u] = -1;
        }
    }
    __syncthreads();
    for (int j = t; j < NBUCK; j += 1024)
        base[j] = atomicAdd(&gfill[j * GSTR], hist[j]);
    __syncthreads();
#pragma unroll
    for (int u = 0; u < 4; u++) {
        if (bin[u] >= 0) {
            int p = base[bin[u]] + lr[u];
            if (p < CAP)
                bpack[(size_t)bin[u] * CAP + p] = make_int2(key[u], __float_as_int(vl[u]));
        }
    }
}

// Pass 2: bucket_base computed in-block via LDS scan over gfill.
__global__ __launch_bounds__(1024) void k_p2(const int2* __restrict__ bpack,
                                             const int* __restrict__ gfill,
                                             int2* __restrict__ cpack,
                                             int* __restrict__ row_off) {
    __shared__ int bb[256];
    __shared__ int cnt[RPB];
    __shared__ int sc[RPB];
    __shared__ int rbase[RPB];
    int b = blockIdx.x, t = threadIdx.x;
    if (t < 256) bb[t] = (t < NBUCK) ? gfill[t * GSTR] : 0;
    __syncthreads();
    for (int off = 1; off < 256; off <<= 1) {
        int x = 0;
        if (t < 256 && t >= off) x = bb[t - off];
        __syncthreads();
        if (t < 256) bb[t] += x;
        __syncthreads();
    }
    int gbase = (b == 0) ? 0 : bb[b - 1];
    if (b == NBUCK - 1 && t == 0) row_off[N_NODES] = bb[NBUCK - 1];
    int n = gfill[b * GSTR];
    if (n > CAP) n = CAP;
    if (t < RPB) cnt[t] = 0;
    __syncthreads();
    int key[20], lr[20];
    float v[20];
#pragma unroll
    for (int u = 0; u < 20; u++) {
        int i = u * 1024 + t;
        if (i < n) {
            int2 p = bpack[(size_t)b * CAP + i];
            key[u] = p.x;
            v[u] = __int_as_float(p.y);
            lr[u] = atomicAdd(&cnt[key[u] & (RPB - 1)], 1);
        } else {
            key[u] = -1;
        }
    }
    __syncthreads();
    if (t < RPB) sc[t] = cnt[t];
    __syncthreads();
    for (int off = 1; off < RPB; off <<= 1) {
        int x = 0;
        if (t < RPB && t >= off) x = sc[t - off];
        __syncthreads();
        if (t < RPB) sc[t] += x;
        __syncthreads();
    }
    if (t < RPB) rbase[t] = (t == 0) ? 0 : sc[t - 1];
    __syncthreads();
    int g0 = b * RPB;
    if (t < RPB && (g0 + t) < N_NODES) row_off[g0 + t] = gbase + rbase[t];
#pragma unroll
    for (int u = 0; u < 20; u++) {
        if (key[u] >= 0) {
            int pos = gbase + rbase[key[u] & (RPB - 1)] + lr[u];
            cpack[pos] = make_int2(key[u] >> BSHIFT, __float_as_int(v[u]));
        }
    }
}

// ---------------- GEMM1 (MFMA): support(fp8, SLICE-MAJOR) = x(f32) @ W1t ----------------
// Single-buffered LDS (30KB) -> 4 blocks/CU (32 waves). Swapped-operand MFMA.
// Output layout: support[slice][row][32] with slice = col>>5 (8 slices of 32 fp8).

#define ASTR 40
#define BSTR 40

__global__ __launch_bounds__(512) void k_gemm1(const float* __restrict__ A,
                                               const u16* __restrict__ Bt,  // [256][512] bf16
                                               u8* __restrict__ Cf8, int M) {
    __shared__ u16 As[128 * ASTR];
    __shared__ u16 Bs[256 * BSTR];
    int tid = threadIdx.x;
    int bm = blockIdx.x * 128;
    int lane = tid & 63, wid = tid >> 6;
    int wm = wid >> 2, wn = wid & 3;

    int s_ar = tid >> 2;
    int s_ak = (tid & 3) * 8;
    int s_bn = tid >> 1;
    int s_bk = (tid & 1) * 16;

    bool arow_ok = (bm + s_ar) < M;
    const float* aptr = A + (size_t)(bm + s_ar) * F_IN + s_ak;
    const u16*   bptr = Bt + (size_t)s_bn * F_IN + s_bk;

    f32x4 acc[4][4];
#pragma unroll
    for (int i = 0; i < 4; i++)
#pragma unroll
        for (int j = 0; j < 4; j++) acc[i][j] = (f32x4){0.f, 0.f, 0.f, 0.f};

    int kg = lane >> 4;
    int r16 = lane & 15;

#pragma unroll 1
    for (int kt = 0; kt < F_IN / 32; kt++) {
        float4 ra0, ra1;
        int4 rb0, rb1;
        const float* ap = aptr + kt * 32;
        if (arow_ok) {
            ra0 = *(const float4*)ap;
            ra1 = *(const float4*)(ap + 4);
        } else {
            ra0 = make_float4(0.f, 0.f, 0.f, 0.f);
            ra1 = ra0;
        }
        const u16* bp = bptr + kt * 32;
        rb0 = *(const int4*)bp;
        rb1 = *(const int4*)(bp + 8);
        __syncthreads();  // prior COMPUTE done reading LDS
        int4 w;
        w.x = pk2(ra0.x, ra0.y);
        w.y = pk2(ra0.z, ra0.w);
        w.z = pk2(ra1.x, ra1.y);
        w.w = pk2(ra1.z, ra1.w);
        *(int4*)&As[s_ar * ASTR + s_ak] = w;
        *(int4*)&Bs[s_bn * BSTR + s_bk] = rb0;
        *(int4*)&Bs[s_bn * BSTR + s_bk + 8] = rb1;
        __syncthreads();
        bf16x8 a[4], b[4];
#pragma unroll
        for (int mt = 0; mt < 4; mt++)
            a[mt] = *(const bf16x8*)&As[(wm * 64 + mt * 16 + r16) * ASTR + kg * 8];
#pragma unroll
        for (int nt = 0; nt < 4; nt++)
            b[nt] = *(const bf16x8*)&Bs[(wn * 64 + nt * 16 + r16) * BSTR + kg * 8];
#pragma unroll
        for (int mt = 0; mt < 4; mt++)
#pragma unroll
            for (int nt = 0; nt < 4; nt++)
                acc[mt][nt] = __builtin_amdgcn_mfma_f32_16x16x32_bf16(
                    b[nt], a[mt], acc[mt][nt], 0, 0, 0);  // swapped: D col = x-row
    }

    // D layout (swapped): x-row = tile + (lane&15), W-col = tile + (lane>>4)*4 + j
    // Sliced store: addr = (wc>>5)*(N_NODES*32) + xr*32 + (wc&31)
#pragma unroll
    for (int mt = 0; mt < 4; mt++) {
        int xr = bm + wm * 64 + mt * 16 + (lane & 15);
        if (xr < M) {
#pragma unroll
            for (int nt = 0; nt < 4; nt++) {
                int wc0 = wn * 64 + nt * 16 + (lane >> 4) * 4;
                u32 d = __builtin_amdgcn_cvt_pk_fp8_f32(acc[mt][nt][0], acc[mt][nt][1], 0u, false);
                d = __builtin_amdgcn_cvt_pk_fp8_f32(acc[mt][nt][2], acc[mt][nt][3], d, true);
                *(u32*)&Cf8[(size_t)(wc0 >> 5) * ((size_t)N_NODES * SLICE_B)
                            + (size_t)xr * SLICE_B + (wc0 & 31)] = d;
            }
        }
    }
}

// ---------------- SPMM1 + bias + relu: h(fp8) = A @ support(fp8 sliced) ----------------
// XCD-sliced: slice = blockIdx&7 (round-robin XCD assignment) -> each XCD's
// gather set is one 3.2MB slice, L2-resident. Wave per row; 8 lanes per edge
// (lane owns 4 features = dword); 8 edges per step; shfl_xor cross-group reduce.

__global__ __launch_bounds__(256) void k_spmm1(const u8* __restrict__ Sslc,
                                               const int2* __restrict__ cpack,
                                               const int* __restrict__ row_off,
                                               const float* __restrict__ b1,
                                               u8* __restrict__ Hb8) {
    int bid = blockIdx.x;
    int slice = bid & 7;
    int rg = bid >> 3;
    int lane = threadIdx.x & 63;
    int row = rg * 4 + (threadIdx.x >> 6);
    int beg = __builtin_amdgcn_readfirstlane(row_off[row]);
    int end = __builtin_amdgcn_readfirstlane(row_off[row + 1]);
    int g = lane >> 3;            // edge slot 0..7
    int f = (lane & 7) * 4;       // feature within slice
    const u8* base = Sslc + (size_t)slice * ((size_t)N_NODES * SLICE_B) + f;
    float acc[4] = {};
#pragma unroll 2
    for (int e = beg; e < end; e += 8) {
        int ei = e + g;
        bool ok = ei < end;
        int2 q = cpack[ok ? ei : beg];
        float vv = ok ? __int_as_float(q.y) : 0.f;
        u32 w = *(const u32*)(base + (size_t)q.x * SLICE_B);
        f32x2 lo = __builtin_amdgcn_cvt_pk_f32_fp8(w, false);
        f32x2 hi = __builtin_amdgcn_cvt_pk_f32_fp8(w, true);
        acc[0] += vv * lo.x;
        acc[1] += vv * lo.y;
        acc[2] += vv * hi.x;
        acc[3] += vv * hi.y;
    }
#pragma unroll
    for (int j = 0; j < 4; j++) {
        acc[j] += __shfl_xor(acc[j], 8);
        acc[j] += __shfl_xor(acc[j], 16);
        acc[j] += __shfl_xor(acc[j], 32);
    }
    if (lane < 8) {
        int fo = slice * SLICE_B + f;
        float4 b = *(const float4*)&b1[fo];
        float h0 = fmaxf(acc[0] + b.x, 0.f);
        float h1 = fmaxf(acc[1] + b.y, 0.f);
        float h2 = fmaxf(acc[2] + b.z, 0.f);
        float h3 = fmaxf(acc[3] + b.w, 0.f);
        u32 d = __builtin_amdgcn_cvt_pk_fp8_f32(h0, h1, 0u, false);
        d = __builtin_amdgcn_cvt_pk_fp8_f32(h2, h3, d, true);
        *(u32*)&Hb8[(size_t)row * HID + fo] = d;
    }
}

// ---------------- GEMM2 (MFMA): S2(fp8) = h(fp8) @ W2t ----------------

#define G2STR 264

__global__ __launch_bounds__(256) void k_gemm2(const u8* __restrict__ Hb8,
                                               const u16* __restrict__ W2t,
                                               u8* __restrict__ S2f8) {
    __shared__ u16 As[64 * G2STR];
    int tid = threadIdx.x;
    int base = blockIdx.x * 64;
    {
        int r = tid >> 2, c0 = (tid & 3) * 64;   // 64 fp8 elems per thread
        const u8* src = Hb8 + (size_t)(base + r) * HID + c0;
        bool ok = (base + r) < N_NODES;
#pragma unroll
        for (int q = 0; q < 4; q++) {
            uint4 dv = ok ? *(const uint4*)(src + q * 16) : make_uint4(0, 0, 0, 0);
            u32 wbuf[8];
            u32 dd[4] = {dv.x, dv.y, dv.z, dv.w};
#pragma unroll
            for (int j = 0; j < 4; j++) {
                f32x2 lo = __builtin_amdgcn_cvt_pk_f32_fp8(dd[j], false);
                f32x2 hi = __builtin_amdgcn_cvt_pk_f32_fp8(dd[j], true);
                wbuf[2 * j]     = pk2(lo.x, lo.y);
                wbuf[2 * j + 1] = pk2(hi.x, hi.y);
            }
            *(int4*)&As[r * G2STR + c0 + q * 16]     = *(int4*)&wbuf[0];
            *(int4*)&As[r * G2STR + c0 + q * 16 + 8] = *(int4*)&wbuf[4];
        }
    }
    __syncthreads();
    int lane = tid & 63, wv = tid >> 6;
    int r16 = lane & 15, kg = lane >> 4;
    f32x4 acc[4];
#pragma unroll
    for (int nt = 0; nt < 4; nt++) acc[nt] = (f32x4){0.f, 0.f, 0.f, 0.f};
#pragma unroll
    for (int ks = 0; ks < 8; ks++) {
        bf16x8 a = *(const bf16x8*)&As[(wv * 16 + r16) * G2STR + ks * 32 + kg * 8];
#pragma unroll
        for (int nt = 0; nt < 4; nt++) {
            bf16x8 b = *(const bf16x8*)&W2t[(size_t)(nt * 16 + r16) * 256 + ks * 32 + kg * 8];
            acc[nt] = __builtin_amdgcn_mfma_f32_16x16x32_bf16(b, a, acc[nt], 0, 0, 0);
        }
    }
    int hr = base + wv * 16 + (lane & 15);
    if (hr < N_NODES) {
#pragma unroll
        for (int nt = 0; nt < 3; nt++) {  // nt=3 -> classes >= 48, all dropped
            int cls0 = nt * 16 + (lane >> 4) * 4;
            if (cls0 < C_OUT) {
                u32 d = __builtin_amdgcn_cvt_pk_fp8_f32(acc[nt][0], acc[nt][1], 0u, false);
                d = __builtin_amdgcn_cvt_pk_fp8_f32(acc[nt][2], acc[nt][3], d, true);
                *(u32*)&S2f8[(size_t)hr * C_OUT + cls0] = d;
            }
        }
    }
}

// ---------------- SPMM2 + bias + softmax/log_softmax (fused) ----------------

__global__ __launch_bounds__(256) void k_spmm2(const u8* __restrict__ S2f8,
                                               const int2* __restrict__ cpack,
                                               const int* __restrict__ row_off,
                                               const float* __restrict__ b2,
                                               float* __restrict__ out_ls,
                                               float* __restrict__ out_sm) {
    __shared__ float red[4][64][4];
    int tid = threadIdx.x;
    int lane = tid & 63, wv = tid >> 6;
    int row = blockIdx.x * 4 + wv;
    int beg = __builtin_amdgcn_readfirstlane(row_off[row]);
    int end = __builtin_amdgcn_readfirstlane(row_off[row + 1]);
    int g = lane / 10;           // edge slot 0..5 (lanes 60-63: g=6, inactive)
    int cb = (lane % 10) * 4;    // class block
    bool act = lane < 60;
    float acc[4] = {};
    for (int e0 = beg; e0 < end; e0 += 6) {
        int ei = e0 + g;
        bool ok = act && (ei < end);
        int2 q = cpack[ok ? ei : beg];
        float vv = ok ? __int_as_float(q.y) : 0.f;
        u32 w = *(const u32*)(S2f8 + (size_t)q.x * C_OUT + cb);
        f32x2 lo = __builtin_amdgcn_cvt_pk_f32_fp8(w, false);
        f32x2 hi = __builtin_amdgcn_cvt_pk_f32_fp8(w, true);
        acc[0] += vv * lo.x;
        acc[1] += vv * lo.y;
        acc[2] += vv * hi.x;
        acc[3] += vv * hi.y;
    }
#pragma unroll
    for (int j = 0; j < 4; j++) red[wv][lane][j] = acc[j];
    __builtin_amdgcn_s_waitcnt(0);  // LDS writes visible within wave
    float v;
    if (lane < C_OUT) {
        int sl = lane >> 2, j = lane & 3;
        float s = 0.f;
#pragma unroll
        for (int gg = 0; gg < 6; gg++) s += red[wv][gg * 10 + sl][j];
        v = s + b2[lane];
    } else {
        v = -1e30f;
    }
    float mx = v;
    for (int s = 32; s; s >>= 1) mx = fmaxf(mx, __shfl_xor(mx, s));
    float e2 = (lane < C_OUT) ? __expf(v - mx) : 0.f;
    float sum = e2;
    for (int s = 32; s; s >>= 1) sum += __shfl_xor(sum, s);
    float ls = v - mx - __logf(sum);
    float sm = e2 / sum;
    if (lane < C_OUT) {
        out_ls[(size_t)row * C_OUT + lane] = ls;
        out_sm[(size_t)row * C_OUT + lane] = sm;
    }
}

// ---------------- launch ----------------

extern "C" void kernel_launch(void* const* d_in, const int* in_sizes, int n_in,
                              void* d_out, int out_size, void* d_ws, size_t ws_size,
                              hipStream_t stream) {
    const float* x    = (const float*)d_in[0];
    const float* W1   = (const float*)d_in[1];
    const float* b1   = (const float*)d_in[2];
    const float* W2   = (const float*)d_in[3];
    const float* b2   = (const float*)d_in[4];
    const int*   erow = (const int*)d_in[5];
    const int*   ecol = (const int*)d_in[6];
    const float* eval = (const float*)d_in[7];
    float* out = (float*)d_out;

    char* w = (char*)d_ws;
    auto alloc = [&](size_t bytes) {
        char* p = w;
        w += (bytes + 255) & ~(size_t)255;
        return p;
    };
    u8*    support = (u8*)   alloc((size_t)N_NODES * HID);               // fp8 sliced, 25.6MB
    u8*    hbuf8   = (u8*)   alloc((size_t)N_NODES * HID);               // fp8, 25.6MB
    int2*  cpack   = (int2*) alloc((size_t)N_EDGES * sizeof(int2));      // 25.6MB
    int2*  bpack   = (int2*) alloc((size_t)NBUCK * CAP * sizeof(int2));  // 32.1MB
    int*   row_off = (int*)  alloc((size_t)(N_NODES + 1) * sizeof(int));
    int*   gfill   = (int*)  alloc((size_t)NBUCK * GSTR * sizeof(int));
    u8*    S2f8    = (u8*)   alloc((size_t)N_NODES * C_OUT);             // fp8, 4MB
    u16*   W2t     = (u16*)  alloc((size_t)64 * 256 * sizeof(u16));
    u16*   W1t     = (u16*)  alloc((size_t)F_IN * HID * sizeof(u16));

    k_prep<<<577, 256, 0, stream>>>(W1, W2, W1t, W2t, gfill);

    int NB1 = (N_EDGES + 4095) / 4096;  // 782
    k_p1<<<NB1, 1024, 0, stream>>>(erow, ecol, eval, gfill, bpack);
    k_p2<<<NBUCK, 1024, 0, stream>>>(bpack, gfill, cpack, row_off);

    k_gemm1<<<(N_NODES + 127) / 128, 512, 0, stream>>>(x, W1t, support, N_NODES);
    k_spmm1<<<(N_NODES / 4) * 8, 256, 0, stream>>>(support, cpack, row_off, b1, hbuf8);
    k_gemm2<<<(N_NODES + 63) / 64, 256, 0, stream>>>(hbuf8, W2t, S2f8);
    k_spmm2<<<N_NODES / 4, 256, 0, stream>>>(S2f8, cpack, row_off, b2,
                                             out, out + (size_t)N_NODES * C_OUT);
}

// Round 15
// 362.727 us; speedup vs baseline: 1.6196x; 1.6196x over previous
//
#include <hip/hip_runtime.h>
#include <hip/hip_bf16.h>

#define N_NODES 100000
#define N_EDGES 3200000
#define F_IN    512
#define HID     256
#define C_OUT   40

#define RPB     512                 // rows per bucket
#define BSHIFT  9
#define NBUCK   196                 // ceil(100000/512)
#define CAP     20480               // slots per bucket (mean 16384 + 32 sigma)
#define GSTR    16                  // gfill padding (ints) -> 64B per counter

typedef unsigned short u16;
typedef unsigned char  u8;
typedef unsigned int   u32;
typedef __attribute__((ext_vector_type(8))) short bf16x8;
typedef __attribute__((ext_vector_type(4))) float f32x4;
typedef __attribute__((ext_vector_type(2))) float f32x2;

__device__ __forceinline__ u16 f2bf(float f) {
    u32 x = __float_as_uint(f);
    return (u16)((x + 0x7fffu + ((x >> 16) & 1u)) >> 16);  // RNE
}
__device__ __forceinline__ u32 pk2(float lo, float hi) {
    return (u32)f2bf(lo) | ((u32)f2bf(hi) << 16);
}

// ---------------- prep: W1 transpose->bf16, W2 pad->bf16, zero gfill ----------------

__global__ __launch_bounds__(256) void k_prep(const float* __restrict__ W1,
                                              const float* __restrict__ W2,
                                              u16* __restrict__ W1t,
                                              u16* __restrict__ W2t,
                                              int* __restrict__ gfill) {
    int b = blockIdx.x, t = threadIdx.x;
    if (b < 512) {                       // W1t[n][k] = bf16(W1[k][n])
        int i = b * 256 + t;             // over 512*256
        int k = i >> 8, n = i & 255;
        W1t[(size_t)n * F_IN + k] = f2bf(W1[i]);
    } else if (b < 576) {                // W2t[n][k], classes 40..63 zero
        int i = (b - 512) * 256 + t;     // over 64*256
        int n = i >> 8, k = i & 255;
        W2t[i] = (n < C_OUT) ? f2bf(W2[k * C_OUT + n]) : (u16)0;
    } else {
        for (int j = t; j < NBUCK * GSTR; j += 256) gfill[j] = 0;
    }
}

// ---------------- CSR build: two-pass bucket counting sort ----------------

__global__ __launch_bounds__(1024) void k_p1(const int* __restrict__ row,
                                             const int* __restrict__ col,
                                             const float* __restrict__ val,
                                             int* __restrict__ gfill,     // [NBUCK*GSTR]
                                             int2* __restrict__ bpack) {  // [NBUCK*CAP]
    __shared__ int hist[NBUCK];
    __shared__ int base[NBUCK];
    int t = threadIdx.x;
    for (int j = t; j < NBUCK; j += 1024) hist[j] = 0;
    __syncthreads();
    int e0 = blockIdx.x * 4096;
    int bin[4], key[4], lr[4];
    float vl[4];
#pragma unroll
    for (int u = 0; u < 4; u++) {
        int i = e0 + u * 1024 + t;
        if (i < N_EDGES) {
            int r = row[i];
            bin[u] = r >> BSHIFT;
            key[u] = (col[i] << BSHIFT) | (r & (RPB - 1));
            vl[u] = val[i];
            lr[u] = atomicAdd(&hist[bin[u]], 1);
        } else {
            bin[u] = -1;
        }
    }
    __syncthreads();
    for (int j = t; j < NBUCK; j += 1024)
        base[j] = atomicAdd(&gfill[j * GSTR], hist[j]);
    __syncthreads();
#pragma unroll
    for (int u = 0; u < 4; u++) {
        if (bin[u] >= 0) {
            int p = base[bin[u]] + lr[u];
            if (p < CAP)
                bpack[(size_t)bin[u] * CAP + p] = make_int2(key[u], __float_as_int(vl[u]));
        }
    }
}

// Pass 2: bucket_base computed in-block via LDS scan over gfill.
__global__ __launch_bounds__(1024) void k_p2(const int2* __restrict__ bpack,
                                             const int* __restrict__ gfill,
                                             int2* __restrict__ cpack,
                                             int* __restrict__ row_off) {
    __shared__ int bb[256];
    __shared__ int cnt[RPB];
    __shared__ int sc[RPB];
    __shared__ int rbase[RPB];
    int b = blockIdx.x, t = threadIdx.x;
    if (t < 256) bb[t] = (t < NBUCK) ? gfill[t * GSTR] : 0;
    __syncthreads();
    for (int off = 1; off < 256; off <<= 1) {
        int x = 0;
        if (t < 256 && t >= off) x = bb[t - off];
        __syncthreads();
        if (t < 256) bb[t] += x;
        __syncthreads();
    }
    int gbase = (b == 0) ? 0 : bb[b - 1];
    if (b == NBUCK - 1 && t == 0) row_off[N_NODES] = bb[NBUCK - 1];
    int n = gfill[b * GSTR];
    if (n > CAP) n = CAP;
    if (t < RPB) cnt[t] = 0;
    __syncthreads();
    int key[20], lr[20];
    float v[20];
#pragma unroll
    for (int u = 0; u < 20; u++) {
        int i = u * 1024 + t;
        if (i < n) {
            int2 p = bpack[(size_t)b * CAP + i];
            key[u] = p.x;
            v[u] = __int_as_float(p.y);
            lr[u] = atomicAdd(&cnt[key[u] & (RPB - 1)], 1);
        } else {
            key[u] = -1;
        }
    }
    __syncthreads();
    if (t < RPB) sc[t] = cnt[t];
    __syncthreads();
    for (int off = 1; off < RPB; off <<= 1) {
        int x = 0;
        if (t < RPB && t >= off) x = sc[t - off];
        __syncthreads();
        if (t < RPB) sc[t] += x;
        __syncthreads();
    }
    if (t < RPB) rbase[t] = (t == 0) ? 0 : sc[t - 1];
    __syncthreads();
    int g0 = b * RPB;
    if (t < RPB && (g0 + t) < N_NODES) row_off[g0 + t] = gbase + rbase[t];
#pragma unroll
    for (int u = 0; u < 20; u++) {
        if (key[u] >= 0) {
            int pos = gbase + rbase[key[u] & (RPB - 1)] + lr[u];
            cpack[pos] = make_int2(key[u] >> BSHIFT, __float_as_int(v[u]));
        }
    }
}

// ---------------- GEMM1 (MFMA): support(fp8) = x(f32) @ W1t ----------------
// Single-buffered LDS (30KB) -> 4 blocks/CU (32 waves) for latency hiding.
// Swapped-operand MFMA: 4 acc regs = 4 consecutive output cols -> dword store.

#define ASTR 40
#define BSTR 40

__global__ __launch_bounds__(512) void k_gemm1(const float* __restrict__ A,
                                               const u16* __restrict__ Bt,  // [256][512] bf16
                                               u8* __restrict__ Cf8, int M) {
    __shared__ u16 As[128 * ASTR];
    __shared__ u16 Bs[256 * BSTR];
    int tid = threadIdx.x;
    int bm = blockIdx.x * 128;
    int lane = tid & 63, wid = tid >> 6;
    int wm = wid >> 2, wn = wid & 3;

    int s_ar = tid >> 2;
    int s_ak = (tid & 3) * 8;
    int s_bn = tid >> 1;
    int s_bk = (tid & 1) * 16;

    bool arow_ok = (bm + s_ar) < M;
    const float* aptr = A + (size_t)(bm + s_ar) * F_IN + s_ak;
    const u16*   bptr = Bt + (size_t)s_bn * F_IN + s_bk;

    f32x4 acc[4][4];
#pragma unroll
    for (int i = 0; i < 4; i++)
#pragma unroll
        for (int j = 0; j < 4; j++) acc[i][j] = (f32x4){0.f, 0.f, 0.f, 0.f};

    int kg = lane >> 4;
    int r16 = lane & 15;

#pragma unroll 1
    for (int kt = 0; kt < F_IN / 32; kt++) {
        float4 ra0, ra1;
        int4 rb0, rb1;
        const float* ap = aptr + kt * 32;
        if (arow_ok) {
            ra0 = *(const float4*)ap;
            ra1 = *(const float4*)(ap + 4);
        } else {
            ra0 = make_float4(0.f, 0.f, 0.f, 0.f);
            ra1 = ra0;
        }
        const u16* bp = bptr + kt * 32;
        rb0 = *(const int4*)bp;
        rb1 = *(const int4*)(bp + 8);
        __syncthreads();  // prior COMPUTE done reading LDS
        int4 w;
        w.x = pk2(ra0.x, ra0.y);
        w.y = pk2(ra0.z, ra0.w);
        w.z = pk2(ra1.x, ra1.y);
        w.w = pk2(ra1.z, ra1.w);
        *(int4*)&As[s_ar * ASTR + s_ak] = w;
        *(int4*)&Bs[s_bn * BSTR + s_bk] = rb0;
        *(int4*)&Bs[s_bn * BSTR + s_bk + 8] = rb1;
        __syncthreads();
        bf16x8 a[4], b[4];
#pragma unroll
        for (int mt = 0; mt < 4; mt++)
            a[mt] = *(const bf16x8*)&As[(wm * 64 + mt * 16 + r16) * ASTR + kg * 8];
#pragma unroll
        for (int nt = 0; nt < 4; nt++)
            b[nt] = *(const bf16x8*)&Bs[(wn * 64 + nt * 16 + r16) * BSTR + kg * 8];
#pragma unroll
        for (int mt = 0; mt < 4; mt++)
#pragma unroll
            for (int nt = 0; nt < 4; nt++)
                acc[mt][nt] = __builtin_amdgcn_mfma_f32_16x16x32_bf16(
                    b[nt], a[mt], acc[mt][nt], 0, 0, 0);  // swapped: D col = x-row
    }

    // D layout (swapped): x-row = tile + (lane&15), W-col = tile + (lane>>4)*4 + j
#pragma unroll
    for (int mt = 0; mt < 4; mt++) {
        int xr = bm + wm * 64 + mt * 16 + (lane & 15);
        if (xr < M) {
#pragma unroll
            for (int nt = 0; nt < 4; nt++) {
                int wc0 = wn * 64 + nt * 16 + (lane >> 4) * 4;
                u32 d = __builtin_amdgcn_cvt_pk_fp8_f32(acc[mt][nt][0], acc[mt][nt][1], 0u, false);
                d = __builtin_amdgcn_cvt_pk_fp8_f32(acc[mt][nt][2], acc[mt][nt][3], d, true);
                *(u32*)&Cf8[(size_t)xr * HID + wc0] = d;
            }
        }
    }
}

// ---------------- SPMM1 + bias + relu: h(fp8) = A @ support(fp8) ----------------

__global__ __launch_bounds__(256) void k_spmm1(const u8* __restrict__ Sf8,
                                               const int2* __restrict__ cpack,
                                               const int* __restrict__ row_off,
                                               const float* __restrict__ b1,
                                               u8* __restrict__ Hb8) {
    int lane = threadIdx.x & 63;
    int row = blockIdx.x * 4 + (threadIdx.x >> 6);
    int beg = __builtin_amdgcn_readfirstlane(row_off[row]);
    int end = __builtin_amdgcn_readfirstlane(row_off[row + 1]);
    int f4 = lane * 4;
    const u8* base = Sf8 + f4;
    float acc[4] = {};
    int e = beg;
    for (; e + 8 <= end; e += 8) {
        int2 q[8];
#pragma unroll
        for (int t = 0; t < 8; t++) q[t] = cpack[e + t];
#pragma unroll
        for (int t = 0; t < 8; t++) {
            float vv = __int_as_float(q[t].y);
            u32 w = *(const u32*)(base + (size_t)q[t].x * HID);
            f32x2 lo = __builtin_amdgcn_cvt_pk_f32_fp8(w, false);
            f32x2 hi = __builtin_amdgcn_cvt_pk_f32_fp8(w, true);
            acc[0] += vv * lo.x;
            acc[1] += vv * lo.y;
            acc[2] += vv * hi.x;
            acc[3] += vv * hi.y;
        }
    }
    for (; e < end; e++) {
        int2 q = cpack[e];
        float vv = __int_as_float(q.y);
        u32 w = *(const u32*)(base + (size_t)q.x * HID);
        f32x2 lo = __builtin_amdgcn_cvt_pk_f32_fp8(w, false);
        f32x2 hi = __builtin_amdgcn_cvt_pk_f32_fp8(w, true);
        acc[0] += vv * lo.x;
        acc[1] += vv * lo.y;
        acc[2] += vv * hi.x;
        acc[3] += vv * hi.y;
    }
    float4 b = *(const float4*)&b1[f4];
    float h0 = fmaxf(acc[0] + b.x, 0.f);
    float h1 = fmaxf(acc[1] + b.y, 0.f);
    float h2 = fmaxf(acc[2] + b.z, 0.f);
    float h3 = fmaxf(acc[3] + b.w, 0.f);
    u32 d = __builtin_amdgcn_cvt_pk_fp8_f32(h0, h1, 0u, false);
    d = __builtin_amdgcn_cvt_pk_fp8_f32(h2, h3, d, true);
    *(u32*)&Hb8[(size_t)row * HID + f4] = d;
}

// ---------------- GEMM2 (MFMA): S2(fp8) = h(fp8) @ W2t ----------------

#define G2STR 264

__global__ __launch_bounds__(256) void k_gemm2(const u8* __restrict__ Hb8,
                                               const u16* __restrict__ W2t,
                                               u8* __restrict__ S2f8) {
    __shared__ u16 As[64 * G2STR];
    int tid = threadIdx.x;
    int base = blockIdx.x * 64;
    {
        int r = tid >> 2, c0 = (tid & 3) * 64;   // 64 fp8 elems per thread
        const u8* src = Hb8 + (size_t)(base + r) * HID + c0;
        bool ok = (base + r) < N_NODES;
#pragma unroll
        for (int q = 0; q < 4; q++) {
            uint4 dv = ok ? *(const uint4*)(src + q * 16) : make_uint4(0, 0, 0, 0);
            u32 wbuf[8];
            u32 dd[4] = {dv.x, dv.y, dv.z, dv.w};
#pragma unroll
            for (int j = 0; j < 4; j++) {
                f32x2 lo = __builtin_amdgcn_cvt_pk_f32_fp8(dd[j], false);
                f32x2 hi = __builtin_amdgcn_cvt_pk_f32_fp8(dd[j], true);
                wbuf[2 * j]     = pk2(lo.x, lo.y);
                wbuf[2 * j + 1] = pk2(hi.x, hi.y);
            }
            *(int4*)&As[r * G2STR + c0 + q * 16]     = *(int4*)&wbuf[0];
            *(int4*)&As[r * G2STR + c0 + q * 16 + 8] = *(int4*)&wbuf[4];
        }
    }
    __syncthreads();
    int lane = tid & 63, wv = tid >> 6;
    int r16 = lane & 15, kg = lane >> 4;
    f32x4 acc[4];
#pragma unroll
    for (int nt = 0; nt < 4; nt++) acc[nt] = (f32x4){0.f, 0.f, 0.f, 0.f};
#pragma unroll
    for (int ks = 0; ks < 8; ks++) {
        bf16x8 a = *(const bf16x8*)&As[(wv * 16 + r16) * G2STR + ks * 32 + kg * 8];
#pragma unroll
        for (int nt = 0; nt < 4; nt++) {
            bf16x8 b = *(const bf16x8*)&W2t[(size_t)(nt * 16 + r16) * 256 + ks * 32 + kg * 8];
            acc[nt] = __builtin_amdgcn_mfma_f32_16x16x32_bf16(b, a, acc[nt], 0, 0, 0);
        }
    }
    int hr = base + wv * 16 + (lane & 15);
    if (hr < N_NODES) {
#pragma unroll
        for (int nt = 0; nt < 3; nt++) {  // nt=3 -> classes >= 48, all dropped
            int cls0 = nt * 16 + (lane >> 4) * 4;
            if (cls0 < C_OUT) {
                u32 d = __builtin_amdgcn_cvt_pk_fp8_f32(acc[nt][0], acc[nt][1], 0u, false);
                d = __builtin_amdgcn_cvt_pk_fp8_f32(acc[nt][2], acc[nt][3], d, true);
                *(u32*)&S2f8[(size_t)hr * C_OUT + cls0] = d;
            }
        }
    }
}

// ---------------- SPMM2 + bias + softmax/log_softmax (fused) ----------------

__global__ __launch_bounds__(256) void k_spmm2(const u8* __restrict__ S2f8,
                                               const int2* __restrict__ cpack,
                                               const int* __restrict__ row_off,
                                               const float* __restrict__ b2,
                                               float* __restrict__ out_ls,
                                               float* __restrict__ out_sm) {
    __shared__ float red[4][64][4];
    int tid = threadIdx.x;
    int lane = tid & 63, wv = tid >> 6;
    int row = blockIdx.x * 4 + wv;
    int beg = __builtin_amdgcn_readfirstlane(row_off[row]);
    int end = __builtin_amdgcn_readfirstlane(row_off[row + 1]);
    int g = lane / 10;           // edge slot 0..5 (lanes 60-63: g=6, inactive)
    int cb = (lane % 10) * 4;    // class block
    bool act = lane < 60;
    float acc[4] = {};
    for (int e0 = beg; e0 < end; e0 += 6) {
        int ei = e0 + g;
        bool ok = act && (ei < end);
        int2 q = cpack[ok ? ei : beg];
        float vv = ok ? __int_as_float(q.y) : 0.f;
        u32 w = *(const u32*)(S2f8 + (size_t)q.x * C_OUT + cb);
        f32x2 lo = __builtin_amdgcn_cvt_pk_f32_fp8(w, false);
        f32x2 hi = __builtin_amdgcn_cvt_pk_f32_fp8(w, true);
        acc[0] += vv * lo.x;
        acc[1] += vv * lo.y;
        acc[2] += vv * hi.x;
        acc[3] += vv * hi.y;
    }
#pragma unroll
    for (int j = 0; j < 4; j++) red[wv][lane][j] = acc[j];
    __builtin_amdgcn_s_waitcnt(0);  // LDS writes visible within wave
    float v;
    if (lane < C_OUT) {
        int sl = lane >> 2, j = lane & 3;
        float s = 0.f;
#pragma unroll
        for (int gg = 0; gg < 6; gg++) s += red[wv][gg * 10 + sl][j];
        v = s + b2[lane];
    } else {
        v = -1e30f;
    }
    float mx = v;
    for (int s = 32; s; s >>= 1) mx = fmaxf(mx, __shfl_xor(mx, s));
    float e2 = (lane < C_OUT) ? __expf(v - mx) : 0.f;
    float sum = e2;
    for (int s = 32; s; s >>= 1) sum += __shfl_xor(sum, s);
    float ls = v - mx - __logf(sum);
    float sm = e2 / sum;
    if (lane < C_OUT) {
        out_ls[(size_t)row * C_OUT + lane] = ls;
        out_sm[(size_t)row * C_OUT + lane] = sm;
    }
}

// ---------------- launch ----------------

extern "C" void kernel_launch(void* const* d_in, const int* in_sizes, int n_in,
                              void* d_out, int out_size, void* d_ws, size_t ws_size,
                              hipStream_t stream) {
    const float* x    = (const float*)d_in[0];
    const float* W1   = (const float*)d_in[1];
    const float* b1   = (const float*)d_in[2];
    const float* W2   = (const float*)d_in[3];
    const float* b2   = (const float*)d_in[4];
    const int*   erow = (const int*)d_in[5];
    const int*   ecol = (const int*)d_in[6];
    const float* eval = (const float*)d_in[7];
    float* out = (float*)d_out;

    char* w = (char*)d_ws;
    auto alloc = [&](size_t bytes) {
        char* p = w;
        w += (bytes + 255) & ~(size_t)255;
        return p;
    };
    u8*    support = (u8*)   alloc((size_t)N_NODES * HID);               // fp8, 25.6MB
    u8*    hbuf8   = (u8*)   alloc((size_t)N_NODES * HID);               // fp8, 25.6MB
    int2*  cpack   = (int2*) alloc((size_t)N_EDGES * sizeof(int2));      // 25.6MB
    int2*  bpack   = (int2*) alloc((size_t)NBUCK * CAP * sizeof(int2));  // 32.1MB
    int*   row_off = (int*)  alloc((size_t)(N_NODES + 1) * sizeof(int));
    int*   gfill   = (int*)  alloc((size_t)NBUCK * GSTR * sizeof(int));
    u8*    S2f8    = (u8*)   alloc((size_t)N_NODES * C_OUT);             // fp8, 4MB
    u16*   W2t     = (u16*)  alloc((size_t)64 * 256 * sizeof(u16));
    u16*   W1t     = (u16*)  alloc((size_t)F_IN * HID * sizeof(u16));

    k_prep<<<577, 256, 0, stream>>>(W1, W2, W1t, W2t, gfill);

    int NB1 = (N_EDGES + 4095) / 4096;  // 782
    k_p1<<<NB1, 1024, 0, stream>>>(erow, ecol, eval, gfill, bpack);
    k_p2<<<NBUCK, 1024, 0, stream>>>(bpack, gfill, cpack, row_off);

    k_gemm1<<<(N_NODES + 127) / 128, 512, 0, stream>>>(x, W1t, support, N_NODES);
    k_spmm1<<<N_NODES / 4, 256, 0, stream>>>(support, cpack, row_off, b1, hbuf8);
    k_gemm2<<<(N_NODES + 63) / 64, 256, 0, stream>>>(hbuf8, W2t, S2f8);
    k_spmm2<<<N_NODES / 4, 256, 0, stream>>>(S2f8, cpack, row_off, b2,
                                             out, out + (size_t)N_NODES * C_OUT);
}